// Round 4
// baseline (5345.234 us; speedup 1.0000x reference)
//
#include <hip/hip_runtime.h>
#include <math.h>

#define BATCH 128
#define TSTEPS 4096
#define INDIM 13
#define XT 64   // steps per x/out LDS tile

// ============================================================================
// R4: 4-phase skeleton kept; LSTM's x+o0 half (cols 0-47) offloaded to a
// partial-GEMM on waves 0/1 during P3 (they were idle), hidden under CfC1.
// P1 shrinks to 8-col chunks (o1/o2) = 32 FMA, seeded from the partial.
// P1 operands preloaded during P4 (o1 final after P3); only k=3 lanes
// (o2 cols, produced in P4) re-read 2 float4 post-barrier.
//
// LDS layout (floats):
//  zL  @0   : 96  [dead 0-47 | o1 @48-70 | 0 @71 | o2 @72-77 | 0...]  (padded)
//  z0  @96  : 64  [x 0-12 | h0 13-47]
//  z1  @160 : 64  [o0 0-34 | h1 35-57 | 0]
//  z2  @224 : 32  [o1 0-22 | h2 23-28 | 0]
//  Pb  @256 : 256 LSTM partial pre-acts, Pb[u*4+A] = cols 0-47 dot
//  xt0 @512 (832) | xt1 @1344 (832)   x tiles, double-buffered
//  ot0 @2176 (384) | ot1 @2560 (384)  out tiles, double-buffered
// ============================================================================

__device__ __forceinline__ float fsig(float x) {
    return __builtin_amdgcn_rcpf(1.f + __expf(-x));
}
__device__ __forceinline__ float ftanh(float x) {
    float s = fsig(x + x);
    return s + s - 1.f;
}
__device__ __forceinline__ float fsoftplus(float x) {
    return (x > 15.f) ? x : __logf(1.f + __expf(x));
}

// quad exchanges via DPP (VALU latency, no LDS pipe)
__device__ __forceinline__ float qxor1(float v) {   // quad_perm [1,0,3,2]
    return __int_as_float(__builtin_amdgcn_update_dpp(
        0, __float_as_int(v), 0xB1, 0xF, 0xF, true));
}
__device__ __forceinline__ float qxor2(float v) {   // quad_perm [2,3,0,1]
    return __int_as_float(__builtin_amdgcn_update_dpp(
        0, __float_as_int(v), 0x4E, 0xF, 0xF, true));
}
#define BFLY4(a) { a += qxor1(a); a += qxor2(a); }

// acc += dot(float4 zv, 4 named weight scalars W_q_{0..3})
#define FMA4(acc, W, q, zv) { acc += zv.x * W##_##q##_0; acc += zv.y * W##_##q##_1; \
                              acc += zv.z * W##_##q##_2; acc += zv.w * W##_##q##_3; }

__global__ __launch_bounds__(256, 1)
void rnn_kernel(const float* __restrict__ x,
                const float* __restrict__ lstm_wi, const float* __restrict__ lstm_wh,
                const float* __restrict__ lstm_b,
                const float* __restrict__ c0w1, const float* __restrict__ c0w2,
                const float* __restrict__ c0wa, const float* __restrict__ c0wb,
                const float* __restrict__ c0b1, const float* __restrict__ c0b2,
                const float* __restrict__ c0ba, const float* __restrict__ c0bb,
                const float* __restrict__ c1w1, const float* __restrict__ c1w2,
                const float* __restrict__ c1wa, const float* __restrict__ c1wb,
                const float* __restrict__ c1b1, const float* __restrict__ c1b2,
                const float* __restrict__ c1ba, const float* __restrict__ c1bb,
                const float* __restrict__ c2w1, const float* __restrict__ c2w2,
                const float* __restrict__ c2wa, const float* __restrict__ c2wb,
                const float* __restrict__ c2b1, const float* __restrict__ c2b2,
                const float* __restrict__ c2ba, const float* __restrict__ c2bb,
                float* __restrict__ out)
{
    const int bb = blockIdx.x;
    const int t  = threadIdx.x;     // 0..255
    const int k  = t & 3;           // K-chunk slot within the quad
    const int u  = t >> 2;          // unit / row-group index 0..63

    __shared__ __align__(16) float smem[2944];
    float* zL  = smem;
    float* z0  = smem + 96;
    float* z1  = smem + 160;
    float* z2  = smem + 224;
    float* Pb  = smem + 256;
    float* xt0 = smem + 512;
    float* xt1 = smem + 1344;
    float* ot0 = smem + 2176;
    float* ot1 = smem + 2560;

    const long xbase = (long)bb * TSTEPS * INDIM;
    const long obase = (long)bb * TSTEPS * 6;

    // ---- LSTM chunk weights (cols 48+8k .. 48+8k+8 of the PADDED layout):
    //  padded col c: 48-70 -> h[c-13] (o1 = h[35..57]); 71 -> 0;
    //                72-77 -> h[c-14] (o2 = h[58..63]); 78+ -> 0
    float wl[4][8];
    #pragma unroll
    for (int A = 0; A < 4; ++A) {
        #pragma unroll
        for (int j = 0; j < 8; ++j) {
            const int c = 48 + 8 * k + j;
            const int r = A * 64 + u;
            float wv = 0.f;
            if (c <= 70)                 wv = lstm_wh[r * 64 + (c - 13)];
            else if (c >= 72 && c <= 77) wv = lstm_wh[r * 64 + (c - 14)];
            wl[A][j] = wv;
        }
    }
    const float bL0 = lstm_b[u];
    const float bL1 = lstm_b[64 + u];
    const float bL2 = lstm_b[128 + u];
    const float bL3 = lstm_b[192 + u];

    // ---- partial-GEMM weights (lanes 0..127): lane j handles LSTM rows
    //  j (u0=j>>2, A=j&3) and j+128 (u1=32+u0), cols 0-47 = [x(13)|o0(35)]
    float wpx0[13], wpx1[13], wpo0[36], wpo1[36];
    {
        const int A  = t & 3;
        const int u0 = (t >> 2) & 31;
        const int u1 = 32 + u0;
        const bool pw = (t < 128);
        #pragma unroll
        for (int c = 0; c < 13; ++c) {
            wpx0[c] = pw ? lstm_wi[(A * 64 + u0) * 13 + c] : 0.f;
            wpx1[c] = pw ? lstm_wi[(A * 64 + u1) * 13 + c] : 0.f;
        }
        #pragma unroll
        for (int c = 0; c < 36; ++c) {
            wpo0[c] = (pw && c < 35) ? lstm_wh[(A * 64 + u0) * 64 + c] : 0.f;
            wpo1[c] = (pw && c < 35) ? lstm_wh[(A * 64 + u1) * 64 + c] : 0.f;
        }
    }

    // ---- CfC weights: quad groups (disjoint lane sets, one name overlay)
    const int grp  = (u < 35) ? 0 : (u < 58) ? 1 : 2;
    const int row  = (grp == 0) ? u : (grp == 1) ? (u - 35) : (u - 58);
    const int rl   = (grp == 0) ? 48 : (grp == 1) ? 58 : 29;
    const int clen = (grp == 0) ? 12 : (grp == 1) ? 16 : 8;
    const int cb   = clen * k;
    const float *W0p, *W1p, *W2p, *W3p;
    float bC0, bC1, bC2, bC3;
    if (grp == 0) {
        W0p = c0w1 + row * 48; W1p = c0w2 + row * 48;
        W2p = c0wa + row * 48; W3p = c0wb + row * 48;
        bC0 = c0b1[row]; bC1 = c0b2[row]; bC2 = c0ba[row]; bC3 = c0bb[row];
    } else if (grp == 1) {
        W0p = c1w1 + row * 58; W1p = c1w2 + row * 58;
        W2p = c1wa + row * 58; W3p = c1wb + row * 58;
        bC0 = c1b1[row]; bC1 = c1b2[row]; bC2 = c1ba[row]; bC3 = c1bb[row];
    } else {
        W0p = c2w1 + row * 29; W1p = c2w2 + row * 29;
        W2p = c2wa + row * 29; W3p = c2wb + row * 29;
        bC0 = c2b1[row]; bC1 = c2b2[row]; bC2 = c2ba[row]; bC3 = c2bb[row];
    }
    auto cwf = [&](const float* W, int c) -> float {
        int cc = cb + c;
        return (c < clen && cc < rl) ? W[cc] : 0.f;
    };
#define DEF_WC(A,q) \
    float wc##A##_##q##_0 = cwf(W##A##p, 4*q + 0); \
    float wc##A##_##q##_1 = cwf(W##A##p, 4*q + 1); \
    float wc##A##_##q##_2 = cwf(W##A##p, 4*q + 2); \
    float wc##A##_##q##_3 = cwf(W##A##p, 4*q + 3);
    DEF_WC(0,0) DEF_WC(0,1) DEF_WC(0,2) DEF_WC(0,3)
    DEF_WC(1,0) DEF_WC(1,1) DEF_WC(1,2) DEF_WC(1,3)
    DEF_WC(2,0) DEF_WC(2,1) DEF_WC(2,2) DEF_WC(2,3)
    DEF_WC(3,0) DEF_WC(3,1) DEF_WC(3,2) DEF_WC(3,3)
#undef DEF_WC

    float creg = 0.f;                         // cell state, replicated per quad

    // ---- prologue: zero state+P, load x tile 0, seed x_0 into z0 ----
    for (int i = t; i < 512; i += 256) smem[i] = 0.f;
    if (t < 208) {                            // 208 float4 = 64 steps x 13
        float4 xi = *(const float4*)(x + xbase + 4 * t);
        *(float4*)&xt0[4 * t] = xi;
    }
    if (t < 13) { z0[t] = x[xbase + t]; }
    __syncthreads();

    // partial-GEMM for ts=0: x_0 from tile row 0, o0^{-1} = 0 (z1 zeroed)
    if (t < 128) {
        float s0 = 0.f, s1 = 0.f;
        #pragma unroll
        for (int c = 0; c < 13; ++c) {
            float xv = xt0[c];
            s0 += xv * wpx0[c]; s1 += xv * wpx1[c];
        }
        #pragma unroll
        for (int i = 0; i < 9; ++i) {
            float4 v = *(const float4*)(z1 + 4 * i);
            s0 += v.x * wpo0[4*i]   + v.y * wpo0[4*i+1]
                + v.z * wpo0[4*i+2] + v.w * wpo0[4*i+3];
            s1 += v.x * wpo1[4*i]   + v.y * wpo1[4*i+1]
                + v.z * wpo1[4*i+2] + v.w * wpo1[4*i+3];
        }
        Pb[t] = s0; Pb[t + 128] = s1;
    }
    __syncthreads();

    // initial preload (zL chunk all-zero at ts=0; Pb fresh)
    float4 q0 = *(const float4*)(zL + 48 + 8 * k);
    float4 q1 = *(const float4*)(zL + 52 + 8 * k);
    float4 pf = {0.f, 0.f, 0.f, 0.f};
    if (k == 0) pf = *(const float4*)(Pb + 4 * u);

    #pragma unroll 1
    for (int ts = 0; ts < TSTEPS; ++ts) {
        const int par = (ts >> 6) & 1;
        const int lts = ts & 63;

        // ---- phase 1: LSTM tail (cols 48+8k) + butterfly + nonlin ----
        {
            // k=3's chunk (o2 cols 72-77) was written in P4 -> re-read
            if (k == 3) {
                q0 = *(const float4*)(zL + 48 + 8 * k);
                q1 = *(const float4*)(zL + 52 + 8 * k);
            }
            float a0 = (k == 0) ? pf.x : 0.f;
            float a1 = (k == 0) ? pf.y : 0.f;
            float a2 = (k == 0) ? pf.z : 0.f;
            float a3 = (k == 0) ? pf.w : 0.f;
            const float qq[8] = {q0.x, q0.y, q0.z, q0.w, q1.x, q1.y, q1.z, q1.w};
            #pragma unroll
            for (int j = 0; j < 8; ++j) {
                a0 += qq[j] * wl[0][j]; a1 += qq[j] * wl[1][j];
                a2 += qq[j] * wl[2][j]; a3 += qq[j] * wl[3][j];
            }
            BFLY4(a0) BFLY4(a1) BFLY4(a2) BFLY4(a3)
            a0 += bL0; a1 += bL1; a2 += bL2; a3 += bL3;   // ia, ig, fg, og
            float cn = creg * fsig(a2 + 1.f) + ftanh(a0) * fsig(a1);
            creg = cn;                      // bit-identical on all 4 quad lanes
            float hl = ftanh(cn) * fsig(a3);
            if (k == 0) {
                if (u < 35)      z0[13 + u] = hl;   // h0
                else if (u < 58) z1[u]      = hl;   // h1 at z1[35..57]
                else             z2[u - 35] = hl;   // h2 at z2[23..28]
            }
        }
        __syncthreads();

        // ---- phase 2: CfC0 (lanes 0..139) || tile refill / out flush ----
        if (grp == 0) {
            const float4* zc = (const float4*)(z0 + 12 * k);
            float4 v0 = zc[0], v1 = zc[1], v2 = zc[2];
            float a0 = 0.f, a1 = 0.f, a2 = 0.f, a3 = 0.f;
            FMA4(a0, wc0, 0, v0) FMA4(a0, wc0, 1, v1) FMA4(a0, wc0, 2, v2)
            FMA4(a1, wc1, 0, v0) FMA4(a1, wc1, 1, v1) FMA4(a1, wc1, 2, v2)
            FMA4(a2, wc2, 0, v0) FMA4(a2, wc2, 1, v1) FMA4(a2, wc2, 2, v2)
            FMA4(a3, wc3, 0, v0) FMA4(a3, wc3, 1, v1) FMA4(a3, wc3, 2, v2)
            BFLY4(a0) BFLY4(a1) BFLY4(a2) BFLY4(a3)
            a0 += bC0; a1 += bC1; a2 += bC2; a3 += bC3;
            float tg = fsig(a2 + a3);
            float f1 = ftanh(a0), f2 = ftanh(a1);
            float o = f1 + tg * (f2 - f1);
            if (k == 0) { z1[row] = o; }               // o0 (CfC1 + P-GEMM src)
        } else {
            if (lts == 62 && (ts + 2) < TSTEPS) {
                // refill x tile [ts+2, ts+66) into buffer par^1 (2 f4/lane)
                int i = (t - 140) * 2;                 // lanes 140..243
                float* dst = par ? xt0 : xt1;
                const float* src = x + xbase + (long)(ts + 2) * 13;
                if (i < 208)     *(float4*)&dst[4*i]     = *(const float4*)(src + 4*i);
                if (i + 1 < 208) *(float4*)&dst[4*(i+1)] = *(const float4*)(src + 4*(i+1));
            }
            if (lts == 0 && ts > 0) {
                // flush out tile for steps [ts-64, ts) from buffer par^1
                int i = t - 140;                       // 0..95 used
                if (i < 96) {
                    const float* src = par ? ot0 : ot1;
                    float4 v = *(const float4*)&src[4 * i];
                    *(float4*)(out + obase + (long)(ts - XT) * 6 + 4 * i) = v;
                }
            }
        }
        __syncthreads();

        // ---- phase 3: CfC1 (lanes 140..231) || LSTM partial-GEMM (0..127)
        //               || x_{t+1} commit (lanes 232..244) ----
        if (grp == 1) {
            const float4* zc = (const float4*)(z1 + 16 * k);
            float4 v0 = zc[0], v1 = zc[1], v2 = zc[2], v3 = zc[3];
            float a0 = 0.f, a1 = 0.f, a2 = 0.f, a3 = 0.f;
            FMA4(a0, wc0, 0, v0) FMA4(a0, wc0, 1, v1) FMA4(a0, wc0, 2, v2) FMA4(a0, wc0, 3, v3)
            FMA4(a1, wc1, 0, v0) FMA4(a1, wc1, 1, v1) FMA4(a1, wc1, 2, v2) FMA4(a1, wc1, 3, v3)
            FMA4(a2, wc2, 0, v0) FMA4(a2, wc2, 1, v1) FMA4(a2, wc2, 2, v2) FMA4(a2, wc2, 3, v3)
            FMA4(a3, wc3, 0, v0) FMA4(a3, wc3, 1, v1) FMA4(a3, wc3, 2, v2) FMA4(a3, wc3, 3, v3)
            BFLY4(a0) BFLY4(a1) BFLY4(a2) BFLY4(a3)
            a0 += bC0; a1 += bC1; a2 += bC2; a3 += bC3;
            float tg = fsig(a2 + a3);
            float f1 = ftanh(a0), f2 = ftanh(a1);
            float o = f1 + tg * (f2 - f1);
            if (k == 0) { z2[row] = o; zL[48 + row] = o; }   // o1
        } else if (t < 128) {
            // LSTM^{t+1} partial: cols 0-47 = [x_{t+1} | o0^t]
            const float* xb = (((ts + 1) >> 6) & 1) ? xt1 : xt0;
            const int xr = ((ts + 1) & 63) * 13;
            float s0 = 0.f, s1 = 0.f;
            #pragma unroll
            for (int c = 0; c < 13; ++c) {
                float xv = xb[xr + c];
                s0 += xv * wpx0[c]; s1 += xv * wpx1[c];
            }
            #pragma unroll
            for (int i = 0; i < 9; ++i) {
                float4 v = *(const float4*)(z1 + 4 * i);
                s0 += v.x * wpo0[4*i]   + v.y * wpo0[4*i+1]
                    + v.z * wpo0[4*i+2] + v.w * wpo0[4*i+3];
                s1 += v.x * wpo1[4*i]   + v.y * wpo1[4*i+1]
                    + v.z * wpo1[4*i+2] + v.w * wpo1[4*i+3];
            }
            Pb[t] = s0; Pb[t + 128] = s1;
        } else if (t >= 232 && t < 245 && (ts + 1) < TSTEPS) {
            // commit x_{t+1} into z0 (CfC0^{t+1} source)
            const float* xb = (((ts + 1) >> 6) & 1) ? xt1 : xt0;
            z0[t - 232] = xb[((ts + 1) & 63) * 13 + (t - 232)];
        }
        __syncthreads();

        // ---- phase 4: preload next-P1 operands + CfC2 (lanes 232..255) ----
        // preload: o1 (final after P3) + Pb (final after P3); k=3's o2 region
        // is being written concurrently by wave 3 -> benign race, re-read in P1
        q0 = *(const float4*)(zL + 48 + 8 * k);
        q1 = *(const float4*)(zL + 52 + 8 * k);
        if (k == 0) pf = *(const float4*)(Pb + 4 * u);
        if (grp == 2) {
            const float4* zc = (const float4*)(z2 + 8 * k);
            float4 v0 = zc[0], v1 = zc[1];
            float a0 = 0.f, a1 = 0.f, a2 = 0.f, a3 = 0.f;
            FMA4(a0, wc0, 0, v0) FMA4(a0, wc0, 1, v1)
            FMA4(a1, wc1, 0, v0) FMA4(a1, wc1, 1, v1)
            FMA4(a2, wc2, 0, v0) FMA4(a2, wc2, 1, v1)
            FMA4(a3, wc3, 0, v0) FMA4(a3, wc3, 1, v1)
            BFLY4(a0) BFLY4(a1) BFLY4(a2) BFLY4(a3)
            a0 += bC0; a1 += bC1; a2 += bC2; a3 += bC3;
            float tg = fsig(a2 + a3);
            float f1 = ftanh(a0), f2 = ftanh(a1);
            float o = f1 + tg * (f2 - f1);
            if (k == 0) {
                zL[72 + row] = o;                      // o2 at padded cols 72-77
                float* ob = par ? ot1 : ot0;           // out tile (LDS only)
                ob[lts * 6 + row] = o;
            }
        }
        __syncthreads();
    }

    // ---- epilogue: flush the last out tile (steps 4032..4095, buffer 1) ----
    if (t < 96) {
        float4 v = *(const float4*)&ot1[4 * t];
        *(float4*)(out + obase + (long)(TSTEPS - XT) * 6 + 4 * t) = v;
    }
}

// ---- head: rewrite pred in place, write unc ----
#define S_GW1 0
#define S_GB1 192
#define S_GW2 224
#define S_GB2 320
#define S_AW1 323
#define S_AB1 515
#define S_AW2 547
#define S_AB2 643
#define S_UW1 646
#define S_UB1 742
#define S_UW2 758
#define S_UB2 854
#define S_TOT 860

__global__ __launch_bounds__(256)
void head_kernel(const float* __restrict__ gw1, const float* __restrict__ gb1,
                 const float* __restrict__ gw2, const float* __restrict__ gb2,
                 const float* __restrict__ aw1, const float* __restrict__ ab1,
                 const float* __restrict__ aw2, const float* __restrict__ ab2,
                 const float* __restrict__ uw1, const float* __restrict__ ub1,
                 const float* __restrict__ uw2, const float* __restrict__ ub2,
                 float* __restrict__ out)
{
    __shared__ float s[S_TOT];
    const int t = threadIdx.x;
    if (t < 192) { s[S_GW1 + t] = gw1[t]; s[S_AW1 + t] = aw1[t]; }
    if (t < 96)  { s[S_GW2 + t] = gw2[t]; s[S_AW2 + t] = aw2[t];
                   s[S_UW1 + t] = uw1[t]; s[S_UW2 + t] = uw2[t]; }
    if (t < 32)  { s[S_GB1 + t] = gb1[t]; s[S_AB1 + t] = ab1[t]; }
    if (t < 16)  { s[S_UB1 + t] = ub1[t]; }
    if (t < 3)   { s[S_GB2 + t] = gb2[t]; s[S_AB2 + t] = ab2[t]; }
    if (t < 6)   { s[S_UB2 + t] = ub2[t]; }
    __syncthreads();

    const long p = (long)blockIdx.x * 256 + t;   // < B*T exactly
    const long base = p * 6;
    float m0 = out[base+0], m1 = out[base+1], m2 = out[base+2];
    float m3 = out[base+3], m4 = out[base+4], m5 = out[base+5];

    float gy0 = s[S_GB2+0], gy1 = s[S_GB2+1], gy2 = s[S_GB2+2];
    float ac0 = s[S_AB2+0], ac1 = s[S_AB2+1], ac2 = s[S_AB2+2];
    #pragma unroll
    for (int i = 0; i < 32; ++i) {
        float hg = s[S_GB1+i] + s[S_GW1+i*6+0]*m0 + s[S_GW1+i*6+1]*m1
                 + s[S_GW1+i*6+2]*m2 + s[S_GW1+i*6+3]*m3
                 + s[S_GW1+i*6+4]*m4 + s[S_GW1+i*6+5]*m5;
        hg = ftanh(hg);
        gy0 += s[S_GW2+i]*hg; gy1 += s[S_GW2+32+i]*hg; gy2 += s[S_GW2+64+i]*hg;
        float ha = s[S_AB1+i] + s[S_AW1+i*6+0]*m0 + s[S_AW1+i*6+1]*m1
                 + s[S_AW1+i*6+2]*m2 + s[S_AW1+i*6+3]*m3
                 + s[S_AW1+i*6+4]*m4 + s[S_AW1+i*6+5]*m5;
        ha = ftanh(ha);
        ac0 += s[S_AW2+i]*ha; ac1 += s[S_AW2+32+i]*ha; ac2 += s[S_AW2+64+i]*ha;
    }
    float u0 = s[S_UB2+0], u1 = s[S_UB2+1], u2 = s[S_UB2+2];
    float u3 = s[S_UB2+3], u4 = s[S_UB2+4], u5 = s[S_UB2+5];
    #pragma unroll
    for (int i = 0; i < 16; ++i) {
        float hu = s[S_UB1+i] + s[S_UW1+i*6+0]*m0 + s[S_UW1+i*6+1]*m1
                 + s[S_UW1+i*6+2]*m2 + s[S_UW1+i*6+3]*m3
                 + s[S_UW1+i*6+4]*m4 + s[S_UW1+i*6+5]*m5;
        hu = fmaxf(hu, 0.f);
        u0 += s[S_UW2+i]*hu;      u1 += s[S_UW2+16+i]*hu; u2 += s[S_UW2+32+i]*hu;
        u3 += s[S_UW2+48+i]*hu;   u4 += s[S_UW2+64+i]*hu; u5 += s[S_UW2+80+i]*hu;
    }
    out[base+0] = gy0; out[base+1] = gy1; out[base+2] = gy2;
    out[base+3] = ac0; out[base+4] = ac1; out[base+5] = ac2;
    const long uoff = (long)BATCH * TSTEPS * 6;
    out[uoff+base+0] = fsoftplus(u0); out[uoff+base+1] = fsoftplus(u1);
    out[uoff+base+2] = fsoftplus(u2); out[uoff+base+3] = fsoftplus(u3);
    out[uoff+base+4] = fsoftplus(u4); out[uoff+base+5] = fsoftplus(u5);
}

extern "C" void kernel_launch(void* const* d_in, const int* in_sizes, int n_in,
                              void* d_out, int out_size, void* d_ws, size_t ws_size,
                              hipStream_t stream) {
    const float* x       = (const float*)d_in[0];
    const float* lstm_wi = (const float*)d_in[1];
    const float* lstm_wh = (const float*)d_in[2];
    const float* lstm_b  = (const float*)d_in[3];
    const float* c0w1 = (const float*)d_in[4];
    const float* c0w2 = (const float*)d_in[5];
    const float* c0wa = (const float*)d_in[6];
    const float* c0wb = (const float*)d_in[7];
    const float* c0b1 = (const float*)d_in[8];
    const float* c0b2 = (const float*)d_in[9];
    const float* c0ba = (const float*)d_in[10];
    const float* c0bb = (const float*)d_in[11];
    const float* c1w1 = (const float*)d_in[12];
    const float* c1w2 = (const float*)d_in[13];
    const float* c1wa = (const float*)d_in[14];
    const float* c1wb = (const float*)d_in[15];
    const float* c1b1 = (const float*)d_in[16];
    const float* c1b2 = (const float*)d_in[17];
    const float* c1ba = (const float*)d_in[18];
    const float* c1bb = (const float*)d_in[19];
    const float* c2w1 = (const float*)d_in[20];
    const float* c2w2 = (const float*)d_in[21];
    const float* c2wa = (const float*)d_in[22];
    const float* c2wb = (const float*)d_in[23];
    const float* c2b1 = (const float*)d_in[24];
    const float* c2b2 = (const float*)d_in[25];
    const float* c2ba = (const float*)d_in[26];
    const float* c2bb = (const float*)d_in[27];
    const float* gw1 = (const float*)d_in[28];
    const float* gb1 = (const float*)d_in[29];
    const float* gw2 = (const float*)d_in[30];
    const float* gb2 = (const float*)d_in[31];
    const float* aw1 = (const float*)d_in[32];
    const float* ab1 = (const float*)d_in[33];
    const float* aw2 = (const float*)d_in[34];
    const float* ab2 = (const float*)d_in[35];
    const float* uw1 = (const float*)d_in[36];
    const float* ub1 = (const float*)d_in[37];
    const float* uw2 = (const float*)d_in[38];
    const float* ub2 = (const float*)d_in[39];
    float* out = (float*)d_out;

    rnn_kernel<<<BATCH, 256, 0, stream>>>(x, lstm_wi, lstm_wh, lstm_b,
        c0w1, c0w2, c0wa, c0wb, c0b1, c0b2, c0ba, c0bb,
        c1w1, c1w2, c1wa, c1wb, c1b1, c1b2, c1ba, c1bb,
        c2w1, c2w2, c2wa, c2wb, c2b1, c2b2, c2ba, c2bb, out);

    head_kernel<<<(BATCH * TSTEPS) / 256, 256, 0, stream>>>(
        gw1, gb1, gw2, gb2, aw1, ab1, aw2, ab2, uw1, ub1, uw2, ub2, out);
}